// Round 2
// baseline (13272.702 us; speedup 1.0000x reference)
//
#include <hip/hip_runtime.h>
#include <hip/hip_fp16.h>

// GRU-D 2-layer recurrent head, MI355X.
// Design R1 (resubmit R2 — prior rounds failed on container acquisition, not kernel):
// one block per batch element (256 blocks x 256 threads), thread j owns hidden
// column j. Weights repacked fp16 into d_ws as [K/8][256][8] (16B coalesced
// uint4 per lane). All math fp32 except weight storage and the LDS broadcast
// copies of the matmul input vectors (fp16). Zero cross-block communication;
// 5 intra-block barriers per timestep.
//
// Expected regime: per-CU L2 weight streaming ~1.33MB/step (~9us) overlapped
// with ~6.5us/step VALU -> ~5ms total. Next-round levers (counter-dependent):
// fdot2 if VALU-bound; fp8 weights or split-H if BW-bound.

#define BB  256
#define TT  512
#define DX  64
#define EE  32
#define DIN 96
#define HH  256

// packed half-weight layout offsets (in halves); each region [nseg][256][8]
#define OFF_W0X_R 0        // Wr0 rows 0..95   (12 segs)
#define OFF_W0X_Z 24576
#define OFF_W0X_H 49152
#define OFF_W0H_R 73728    // Wr0 rows 96..351 (32 segs)
#define OFF_W0H_Z 139264
#define OFF_W0H_H 204800
#define OFF_W1X_R 270336   // Wr1 rows 0..255
#define OFF_W1X_Z 335872
#define OFF_W1X_H 401408
#define OFF_W1H_R 466944   // Wr1 rows 256..511
#define OFF_W1H_Z 532480
#define OFF_W1H_H 598016
#define PACK_TOTAL 663552  // halves = 1.33 MB

__global__ void pack_weights(const float* __restrict__ Wr0, const float* __restrict__ Wz0,
                             const float* __restrict__ Wh0, const float* __restrict__ Wr1,
                             const float* __restrict__ Wz1, const float* __restrict__ Wh1,
                             __half* __restrict__ dst) {
  int idx = blockIdx.x * blockDim.x + threadIdx.x;
  if (idx >= PACK_TOTAL) return;
  const float* src;
  int row0, local;
  if (idx < 73728) {                       // x-part of layer0: K=96
    int r = idx / 24576; local = idx % 24576;
    src = (r == 0) ? Wr0 : (r == 1) ? Wz0 : Wh0;
    row0 = 0;
  } else {
    int q = (idx - 73728) / 65536; local = (idx - 73728) % 65536;
    if (q < 3)      { src = (q == 0) ? Wr0 : (q == 1) ? Wz0 : Wh0; row0 = 96;  }
    else if (q < 6) { src = (q == 3) ? Wr1 : (q == 4) ? Wz1 : Wh1; row0 = 0;   }
    else            { src = (q == 6) ? Wr1 : (q == 7) ? Wz1 : Wh1; row0 = 256; }
  }
  int k8 = local >> 11;          // segment (8 K-rows)
  int j  = (local >> 3) & 255;   // output column
  int i  = local & 7;            // K within segment
  dst[idx] = __float2half(src[(size_t)(row0 + k8 * 8 + i) * HH + j]);
}

__device__ __forceinline__ float dot8(const uint4 w, const uint4 v, float acc) {
  union { unsigned u; __half2 h; } cw, cv;
  float2 wf, vf;
  cw.u = w.x; cv.u = v.x; wf = __half22float2(cw.h); vf = __half22float2(cv.h);
  acc = fmaf(wf.x, vf.x, acc); acc = fmaf(wf.y, vf.y, acc);
  cw.u = w.y; cv.u = v.y; wf = __half22float2(cw.h); vf = __half22float2(cv.h);
  acc = fmaf(wf.x, vf.x, acc); acc = fmaf(wf.y, vf.y, acc);
  cw.u = w.z; cv.u = v.z; wf = __half22float2(cw.h); vf = __half22float2(cv.h);
  acc = fmaf(wf.x, vf.x, acc); acc = fmaf(wf.y, vf.y, acc);
  cw.u = w.w; cv.u = v.w; wf = __half22float2(cw.h); vf = __half22float2(cv.h);
  acc = fmaf(wf.x, vf.x, acc); acc = fmaf(wf.y, vf.y, acc);
  return acc;
}

__device__ __forceinline__ float sigm(float x) { return 1.f / (1.f + __expf(-x)); }

__global__ __launch_bounds__(256) void grud_fused(
    const float* __restrict__ x, const float* __restrict__ mask,
    const float* __restrict__ delta, const float* __restrict__ xl,
    const int* __restrict__ sidx, const float* __restrict__ emb,
    const float* __restrict__ gx0, const float* __restrict__ gh0,
    const float* __restrict__ br0, const float* __restrict__ bz0, const float* __restrict__ bh0,
    const float* __restrict__ br1, const float* __restrict__ bz1, const float* __restrict__ bh1,
    const float* __restrict__ Wp1, const float* __restrict__ bp1,
    const float* __restrict__ Wp2, const float* __restrict__ bp2,
    const __half* __restrict__ PW, float* __restrict__ out)
{
  const int b = blockIdx.x;
  const int j = threadIdx.x;

  __shared__ __align__(16) __half xfh[DIN];    // x_filled (fp16 copy for dots)
  __shared__ __align__(16) __half hdech[HH];   // h_decay * h0_prev
  __shared__ __align__(16) __half rhh[HH];     // r * h_dec (reused by both layers)
  __shared__ __align__(16) __half h0h[HH];
  __shared__ __align__(16) __half h1h[HH];
  __shared__ float h1f[HH];
  __shared__ float p1f[HH];
  __shared__ float sdel;

  const float brj0 = br0[j], bzj0 = bz0[j], bhj0 = bh0[j];
  const float brj1 = br1[j], bzj1 = bz1[j], bhj1 = bh1[j];
  const float gh0j = gh0[j];
  float gx0j = 0.f;
  if (j < DX) gx0j = gx0[j];

  h0h[j] = __float2half(0.f);
  h1h[j] = __float2half(0.f);
  if (j < EE) xfh[DX + j] = __float2half(emb[(size_t)sidx[b] * EE + j]);  // const over t
  float h0j = 0.f, h1j = 0.f;

  const size_t xoff = (size_t)b * TT * DX;
  const uint4* W0XR = reinterpret_cast<const uint4*>(PW + OFF_W0X_R);
  const uint4* W0XZ = reinterpret_cast<const uint4*>(PW + OFF_W0X_Z);
  const uint4* W0XH = reinterpret_cast<const uint4*>(PW + OFF_W0X_H);
  const uint4* W0HR = reinterpret_cast<const uint4*>(PW + OFF_W0H_R);
  const uint4* W0HZ = reinterpret_cast<const uint4*>(PW + OFF_W0H_Z);
  const uint4* W0HH = reinterpret_cast<const uint4*>(PW + OFF_W0H_H);
  const uint4* W1XR = reinterpret_cast<const uint4*>(PW + OFF_W1X_R);
  const uint4* W1XZ = reinterpret_cast<const uint4*>(PW + OFF_W1X_Z);
  const uint4* W1XH = reinterpret_cast<const uint4*>(PW + OFF_W1X_H);
  const uint4* W1HR = reinterpret_cast<const uint4*>(PW + OFF_W1H_R);
  const uint4* W1HZ = reinterpret_cast<const uint4*>(PW + OFF_W1H_Z);
  const uint4* W1HH = reinterpret_cast<const uint4*>(PW + OFF_W1H_H);
  __syncthreads();

  for (int t = 0; t < TT; ++t) {
    // ---- P0: x_filled (real slots) + mean-delta scalar ----
    if (j < DX) {
      size_t a = xoff + (size_t)t * DX + j;
      float xv = x[a], mv = mask[a], dv = delta[a], xlv = xl[a];
      float xd = __expf(-fmaxf(dv * gx0j, 0.f)) * xlv;
      xfh[j] = __float2half(mv > 0.f ? xv : xd);
      float s = dv;
      #pragma unroll
      for (int o = 32; o > 0; o >>= 1) s += __shfl_down(s, o, 64);
      if (j == 0) sdel = s * (1.f / 96.f);
    }
    __syncthreads();
    // ---- P1: h_dec = exp(-relu(sdel*gh0)) * h0 ----
    float hd = __expf(-fmaxf(sdel * gh0j, 0.f));
    float hdecj = hd * h0j;
    hdech[j] = __float2half(hdecj);
    __syncthreads();
    // ---- P2: layer0 r,z pre-acts + x-part of h_tilde ----
    float ar = brj0, az = bzj0, ah = bhj0;
    #pragma unroll 4
    for (int k8 = 0; k8 < 12; ++k8) {
      uint4 v = *reinterpret_cast<const uint4*>(xfh + k8 * 8);
      ar = dot8(W0XR[k8 * HH + j], v, ar);
      az = dot8(W0XZ[k8 * HH + j], v, az);
      ah = dot8(W0XH[k8 * HH + j], v, ah);
    }
    #pragma unroll 4
    for (int k8 = 0; k8 < 32; ++k8) {
      uint4 v = *reinterpret_cast<const uint4*>(hdech + k8 * 8);
      ar = dot8(W0HR[k8 * HH + j], v, ar);
      az = dot8(W0HZ[k8 * HH + j], v, az);
    }
    float r = sigm(ar);
    float z = sigm(az);
    rhh[j] = __float2half(r * hdecj);
    __syncthreads();
    // ---- P3: layer0 h_tilde, h0 update ----
    #pragma unroll 4
    for (int k8 = 0; k8 < 32; ++k8) {
      uint4 v = *reinterpret_cast<const uint4*>(rhh + k8 * 8);
      ah = dot8(W0HH[k8 * HH + j], v, ah);
    }
    float ht = tanhf(ah);
    h0j = (1.f - z) * hdecj + z * ht;
    h0h[j] = __float2half(h0j);
    __syncthreads();
    // ---- P4: layer1 r,z pre-acts + h0-part of h_tilde ----
    float ar1 = brj1, az1 = bzj1, ah1 = bhj1;
    #pragma unroll 4
    for (int k8 = 0; k8 < 32; ++k8) {
      uint4 v0 = *reinterpret_cast<const uint4*>(h0h + k8 * 8);
      ar1 = dot8(W1XR[k8 * HH + j], v0, ar1);
      az1 = dot8(W1XZ[k8 * HH + j], v0, az1);
      ah1 = dot8(W1XH[k8 * HH + j], v0, ah1);
      uint4 v1 = *reinterpret_cast<const uint4*>(h1h + k8 * 8);
      ar1 = dot8(W1HR[k8 * HH + j], v1, ar1);
      az1 = dot8(W1HZ[k8 * HH + j], v1, az1);
    }
    float r1 = sigm(ar1);
    float z1 = sigm(az1);
    rhh[j] = __float2half(r1 * h1j);
    __syncthreads();
    // ---- P5: layer1 h_tilde, h1 update (no trailing barrier needed) ----
    #pragma unroll 4
    for (int k8 = 0; k8 < 32; ++k8) {
      uint4 v = *reinterpret_cast<const uint4*>(rhh + k8 * 8);
      ah1 = dot8(W1HH[k8 * HH + j], v, ah1);
    }
    float ht1 = tanhf(ah1);
    h1j = (1.f - z1) * h1j + z1 * ht1;
    h1h[j] = __float2half(h1j);
  }

  // ---- head: out = relu(h1 @ Wp1 + bp1) @ Wp2 + bp2, fp32 throughout ----
  h1f[j] = h1j;
  __syncthreads();
  float a1 = bp1[j];
  #pragma unroll 8
  for (int k = 0; k < HH; ++k) a1 = fmaf(h1f[k], Wp1[(size_t)k * HH + j], a1);
  p1f[j] = fmaxf(a1, 0.f);
  __syncthreads();
  if (j < 48) {
    float o = bp2[j];
    #pragma unroll 8
    for (int k = 0; k < HH; ++k) o = fmaf(p1f[k], Wp2[(size_t)k * 48 + j], o);
    out[(size_t)b * 48 + j] = o;
  }
}

extern "C" void kernel_launch(void* const* d_in, const int* in_sizes, int n_in,
                              void* d_out, int out_size, void* d_ws, size_t ws_size,
                              hipStream_t stream) {
  const float* x    = (const float*)d_in[0];
  const float* mask = (const float*)d_in[1];
  const float* delta= (const float*)d_in[2];
  const float* xl   = (const float*)d_in[3];
  const int*   sidx = (const int*)d_in[4];
  const float* emb  = (const float*)d_in[5];
  const float* gx0  = (const float*)d_in[6];
  const float* gh0  = (const float*)d_in[7];
  const float* Wr0  = (const float*)d_in[8];
  const float* br0  = (const float*)d_in[9];
  const float* Wz0  = (const float*)d_in[10];
  const float* bz0  = (const float*)d_in[11];
  const float* Wh0  = (const float*)d_in[12];
  const float* bh0  = (const float*)d_in[13];
  // d_in[14]=gx1, d_in[15]=gh1: mathematically inert (layer1 delta==0)
  const float* Wr1  = (const float*)d_in[16];
  const float* br1  = (const float*)d_in[17];
  const float* Wz1  = (const float*)d_in[18];
  const float* bz1  = (const float*)d_in[19];
  const float* Wh1  = (const float*)d_in[20];
  const float* bh1  = (const float*)d_in[21];
  const float* Wp1  = (const float*)d_in[22];
  const float* bp1  = (const float*)d_in[23];
  const float* Wp2  = (const float*)d_in[24];
  const float* bp2  = (const float*)d_in[25];
  __half* PW = (__half*)d_ws;          // 1.33 MB used; re-packed every call
  float* out = (float*)d_out;

  hipLaunchKernelGGL(pack_weights, dim3((PACK_TOTAL + 255) / 256), dim3(256), 0, stream,
                     Wr0, Wz0, Wh0, Wr1, Wz1, Wh1, PW);
  hipLaunchKernelGGL(grud_fused, dim3(BB), dim3(256), 0, stream,
                     x, mask, delta, xl, sidx, emb, gx0, gh0,
                     br0, bz0, bh0, br1, bz1, bh1, Wp1, bp1, Wp2, bp2, PW, out);
}

// Round 4
// 5793.061 us; speedup vs baseline: 2.2911x; 2.2911x over previous
//
#include <hip/hip_runtime.h>
#include <hip/hip_fp16.h>

// GRU-D 2-layer recurrent head, MI355X.
// Design R4 = R3 with the bias bug fixed: K-split partial accumulators must
// init to ZERO, bias added once AFTER the 4-way shfl reduction (R3 added the
// bias in all 4 splits -> 4x bias -> absmax 5.9e-2 fail).
// Structure: 256 blocks x 1024 threads; thread (j,s) = (tid>>2, tid&3) owns a
// quarter of each dot's K range; v_dot2_f32_f16 for the dot math; fp16 weights
// packed [seg][256][4][8] in d_ws (consecutive tid -> consecutive 16B words).

#define BB  256
#define TT  512
#define DX  64
#define EE  32
#define DIN 96
#define HH  256

// packed half-weight offsets (in halves); region layout [K/32][256][4][8]
#define OFF_W0X_R 0        // K=96 regions: 3 segs * 8192
#define OFF_W0X_Z 24576
#define OFF_W0X_H 49152
#define OFF_W0H_R 73728    // K=256 regions: 8 segs * 8192
#define OFF_W0H_Z 139264
#define OFF_W0H_H 204800
#define OFF_W1X_R 270336
#define OFF_W1X_Z 335872
#define OFF_W1X_H 401408
#define OFF_W1H_R 466944
#define OFF_W1H_Z 532480
#define OFF_W1H_H 598016
#define PACK_TOTAL 663552  // halves = 1.33 MB

typedef _Float16 half2_t __attribute__((ext_vector_type(2)));

__global__ void pack_weights(const float* __restrict__ Wr0, const float* __restrict__ Wz0,
                             const float* __restrict__ Wh0, const float* __restrict__ Wr1,
                             const float* __restrict__ Wz1, const float* __restrict__ Wh1,
                             __half* __restrict__ dst) {
  int idx = blockIdx.x * blockDim.x + threadIdx.x;
  if (idx >= PACK_TOTAL) return;
  const float* src;
  int row0, local;
  if (idx < 73728) {                       // x-part of layer0: K=96
    int r = idx / 24576; local = idx % 24576;
    src = (r == 0) ? Wr0 : (r == 1) ? Wz0 : Wh0;
    row0 = 0;
  } else {
    int q = (idx - 73728) / 65536; local = (idx - 73728) % 65536;
    if (q < 3)      { src = (q == 0) ? Wr0 : (q == 1) ? Wz0 : Wh0; row0 = 96;  }
    else if (q < 6) { src = (q == 3) ? Wr1 : (q == 4) ? Wz1 : Wh1; row0 = 0;   }
    else            { src = (q == 6) ? Wr1 : (q == 7) ? Wz1 : Wh1; row0 = 256; }
  }
  // region layout: [seg][j:256][s:4][i:8]; source K-row = seg*32 + s*8 + i
  int seg = local >> 13;
  int rem = local & 8191;
  int j   = rem >> 5;
  int s   = (rem >> 3) & 3;
  int i   = rem & 7;
  int row = row0 + seg * 32 + s * 8 + i;
  dst[idx] = __float2half(src[(size_t)row * HH + j]);
}

__device__ __forceinline__ float dot8(uint4 w, uint4 v, float acc) {
#if __has_builtin(__builtin_amdgcn_fdot2)
  union { uint4 u; half2_t h[4]; } W, V;
  W.u = w; V.u = v;
  acc = __builtin_amdgcn_fdot2(W.h[0], V.h[0], acc, false);
  acc = __builtin_amdgcn_fdot2(W.h[1], V.h[1], acc, false);
  acc = __builtin_amdgcn_fdot2(W.h[2], V.h[2], acc, false);
  acc = __builtin_amdgcn_fdot2(W.h[3], V.h[3], acc, false);
#else
  union { unsigned u; __half2 h; } cw, cv;
  float2 wf, vf;
  cw.u = w.x; cv.u = v.x; wf = __half22float2(cw.h); vf = __half22float2(cv.h);
  acc = fmaf(wf.x, vf.x, acc); acc = fmaf(wf.y, vf.y, acc);
  cw.u = w.y; cv.u = v.y; wf = __half22float2(cw.h); vf = __half22float2(cv.h);
  acc = fmaf(wf.x, vf.x, acc); acc = fmaf(wf.y, vf.y, acc);
  cw.u = w.z; cv.u = v.z; wf = __half22float2(cw.h); vf = __half22float2(cv.h);
  acc = fmaf(wf.x, vf.x, acc); acc = fmaf(wf.y, vf.y, acc);
  cw.u = w.w; cv.u = v.w; wf = __half22float2(cw.h); vf = __half22float2(cv.h);
  acc = fmaf(wf.x, vf.x, acc); acc = fmaf(wf.y, vf.y, acc);
#endif
  return acc;
}

__device__ __forceinline__ float kred(float a) {   // combine 4 K-split partials
  a += __shfl_xor(a, 1, 64);
  a += __shfl_xor(a, 2, 64);
  return a;
}

__device__ __forceinline__ float sigm(float x) { return 1.f / (1.f + __expf(-x)); }

__global__ __launch_bounds__(1024) void grud_fused(
    const float* __restrict__ x, const float* __restrict__ mask,
    const float* __restrict__ delta, const float* __restrict__ xl,
    const int* __restrict__ sidx, const float* __restrict__ emb,
    const float* __restrict__ gx0, const float* __restrict__ gh0,
    const float* __restrict__ br0, const float* __restrict__ bz0, const float* __restrict__ bh0,
    const float* __restrict__ br1, const float* __restrict__ bz1, const float* __restrict__ bh1,
    const float* __restrict__ Wp1, const float* __restrict__ bp1,
    const float* __restrict__ Wp2, const float* __restrict__ bp2,
    const __half* __restrict__ PW, float* __restrict__ out)
{
  const int b   = blockIdx.x;
  const int tid = threadIdx.x;
  const int j   = tid >> 2;      // hidden column 0..255
  const int s   = tid & 3;       // K-split 0..3
  const int s8  = s * 8;         // half-offset of this split's slice in a segment
  const int jb  = j * 4 + s;     // uint4 index within a segment

  __shared__ __align__(16) __half xfh[DIN];    // x_filled (fp16, for dots)
  __shared__ __align__(16) __half hdech[HH];   // h_decay * h0_prev
  __shared__ __align__(16) __half rhh[HH];     // r * h_dec (reused by both layers)
  __shared__ __align__(16) __half h0h[HH];
  __shared__ __align__(16) __half h1h[HH];
  __shared__ float h1f[HH];
  __shared__ float p1f[HH];
  __shared__ float sdel;

  const float brj0 = br0[j], bzj0 = bz0[j], bhj0 = bh0[j];
  const float brj1 = br1[j], bzj1 = bz1[j], bhj1 = bh1[j];
  const float gh0j = gh0[j];
  float gx0j = 0.f;
  if (tid < DX) gx0j = gx0[tid];

  if (tid < HH) { h0h[tid] = __float2half(0.f); h1h[tid] = __float2half(0.f); }
  if (tid < EE) xfh[DX + tid] = __float2half(emb[(size_t)sidx[b] * EE + tid]); // const over t
  float h0j = 0.f, h1j = 0.f;

  const size_t xoff = (size_t)b * TT * DX;
  const uint4* W0XR = reinterpret_cast<const uint4*>(PW + OFF_W0X_R);
  const uint4* W0XZ = reinterpret_cast<const uint4*>(PW + OFF_W0X_Z);
  const uint4* W0XH = reinterpret_cast<const uint4*>(PW + OFF_W0X_H);
  const uint4* W0HR = reinterpret_cast<const uint4*>(PW + OFF_W0H_R);
  const uint4* W0HZ = reinterpret_cast<const uint4*>(PW + OFF_W0H_Z);
  const uint4* W0HH = reinterpret_cast<const uint4*>(PW + OFF_W0H_H);
  const uint4* W1XR = reinterpret_cast<const uint4*>(PW + OFF_W1X_R);
  const uint4* W1XZ = reinterpret_cast<const uint4*>(PW + OFF_W1X_Z);
  const uint4* W1XH = reinterpret_cast<const uint4*>(PW + OFF_W1X_H);
  const uint4* W1HR = reinterpret_cast<const uint4*>(PW + OFF_W1H_R);
  const uint4* W1HZ = reinterpret_cast<const uint4*>(PW + OFF_W1H_Z);
  const uint4* W1HH = reinterpret_cast<const uint4*>(PW + OFF_W1H_H);
  __syncthreads();

  for (int t = 0; t < TT; ++t) {
    // ---- P0: x_filled (real slots, wave 0) + mean-delta scalar ----
    if (tid < DX) {
      size_t a = xoff + (size_t)t * DX + tid;
      float xv = x[a], mv = mask[a], dv = delta[a], xlv = xl[a];
      float xd = __expf(-fmaxf(dv * gx0j, 0.f)) * xlv;
      xfh[tid] = __float2half(mv > 0.f ? xv : xd);
      float ssum = dv;
      #pragma unroll
      for (int o = 32; o > 0; o >>= 1) ssum += __shfl_down(ssum, o, 64);
      if (tid == 0) sdel = ssum * (1.f / 96.f);
    }
    __syncthreads();
    // ---- P1: h_dec = exp(-relu(sdel*gh0)) * h0 (redundant across s) ----
    float hd = __expf(-fmaxf(sdel * gh0j, 0.f));
    float hdecj = hd * h0j;
    if (s == 0) hdech[j] = __float2half(hdecj);
    __syncthreads();
    // ---- P2: layer0 r,z pre-acts + x-part of h_tilde (acc init 0; bias after kred!) ----
    float ar = 0.f, az = 0.f, ah = 0.f;
    #pragma unroll
    for (int seg = 0; seg < 3; ++seg) {
      uint4 v = *reinterpret_cast<const uint4*>(xfh + seg * 32 + s8);
      int wi = seg * 1024 + jb;
      ar = dot8(W0XR[wi], v, ar);
      az = dot8(W0XZ[wi], v, az);
      ah = dot8(W0XH[wi], v, ah);
    }
    #pragma unroll 4
    for (int seg = 0; seg < 8; ++seg) {
      uint4 v = *reinterpret_cast<const uint4*>(hdech + seg * 32 + s8);
      int wi = seg * 1024 + jb;
      ar = dot8(W0HR[wi], v, ar);
      az = dot8(W0HZ[wi], v, az);
    }
    ar = kred(ar) + brj0;
    az = kred(az) + bzj0;
    float r = sigm(ar);
    float z = sigm(az);
    if (s == 0) rhh[j] = __float2half(r * hdecj);
    __syncthreads();
    // ---- P3: layer0 h_tilde, h0 update ----
    #pragma unroll 4
    for (int seg = 0; seg < 8; ++seg) {
      uint4 v = *reinterpret_cast<const uint4*>(rhh + seg * 32 + s8);
      ah = dot8(W0HH[seg * 1024 + jb], v, ah);
    }
    ah = kred(ah) + bhj0;
    float ht = tanhf(ah);
    h0j = (1.f - z) * hdecj + z * ht;
    if (s == 0) h0h[j] = __float2half(h0j);
    __syncthreads();
    // ---- P4: layer1 r,z pre-acts + h0-part of h_tilde (acc init 0) ----
    float ar1 = 0.f, az1 = 0.f, ah1 = 0.f;
    #pragma unroll 2
    for (int seg = 0; seg < 8; ++seg) {
      uint4 v0 = *reinterpret_cast<const uint4*>(h0h + seg * 32 + s8);
      uint4 v1 = *reinterpret_cast<const uint4*>(h1h + seg * 32 + s8);
      int wi = seg * 1024 + jb;
      ar1 = dot8(W1XR[wi], v0, ar1);
      az1 = dot8(W1XZ[wi], v0, az1);
      ah1 = dot8(W1XH[wi], v0, ah1);
      ar1 = dot8(W1HR[wi], v1, ar1);
      az1 = dot8(W1HZ[wi], v1, az1);
    }
    ar1 = kred(ar1) + brj1;
    az1 = kred(az1) + bzj1;
    float r1 = sigm(ar1);
    float z1 = sigm(az1);
    if (s == 0) rhh[j] = __float2half(r1 * h1j);
    __syncthreads();
    // ---- P5: layer1 h_tilde, h1 update (no trailing barrier needed) ----
    #pragma unroll 4
    for (int seg = 0; seg < 8; ++seg) {
      uint4 v = *reinterpret_cast<const uint4*>(rhh + seg * 32 + s8);
      ah1 = dot8(W1HH[seg * 1024 + jb], v, ah1);
    }
    ah1 = kred(ah1) + bhj1;
    float ht1 = tanhf(ah1);
    h1j = (1.f - z1) * h1j + z1 * ht1;
    if (s == 0) h1h[j] = __float2half(h1j);
  }

  // ---- head: out = relu(h1 @ Wp1 + bp1) @ Wp2 + bp2, fp32, K-split too ----
  if (s == 0) h1f[j] = h1j;
  __syncthreads();
  {
    float a1 = 0.f;
    int k0 = s * 64;
    #pragma unroll 8
    for (int k = 0; k < 64; ++k) a1 = fmaf(h1f[k0 + k], Wp1[(size_t)(k0 + k) * HH + j], a1);
    a1 = kred(a1) + bp1[j];
    if (s == 0) p1f[j] = fmaxf(a1, 0.f);
  }
  __syncthreads();
  if (tid < 192) {
    int jo = tid >> 2, so = tid & 3;   // 48 outputs x 4 splits
    float o = 0.f;
    int k0 = so * 64;
    #pragma unroll 8
    for (int k = 0; k < 64; ++k) o = fmaf(p1f[k0 + k], Wp2[(size_t)(k0 + k) * 48 + jo], o);
    o += __shfl_xor(o, 1, 64);
    o += __shfl_xor(o, 2, 64);
    if (so == 0) out[(size_t)b * 48 + jo] = o + bp2[jo];
  }
}

extern "C" void kernel_launch(void* const* d_in, const int* in_sizes, int n_in,
                              void* d_out, int out_size, void* d_ws, size_t ws_size,
                              hipStream_t stream) {
  const float* x    = (const float*)d_in[0];
  const float* mask = (const float*)d_in[1];
  const float* delta= (const float*)d_in[2];
  const float* xl   = (const float*)d_in[3];
  const int*   sidx = (const int*)d_in[4];
  const float* emb  = (const float*)d_in[5];
  const float* gx0  = (const float*)d_in[6];
  const float* gh0  = (const float*)d_in[7];
  const float* Wr0  = (const float*)d_in[8];
  const float* br0  = (const float*)d_in[9];
  const float* Wz0  = (const float*)d_in[10];
  const float* bz0  = (const float*)d_in[11];
  const float* Wh0  = (const float*)d_in[12];
  const float* bh0  = (const float*)d_in[13];
  // d_in[14]=gx1, d_in[15]=gh1: mathematically inert (layer1 delta==0)
  const float* Wr1  = (const float*)d_in[16];
  const float* br1  = (const float*)d_in[17];
  const float* Wz1  = (const float*)d_in[18];
  const float* bz1  = (const float*)d_in[19];
  const float* Wh1  = (const float*)d_in[20];
  const float* bh1  = (const float*)d_in[21];
  const float* Wp1  = (const float*)d_in[22];
  const float* bp1  = (const float*)d_in[23];
  const float* Wp2  = (const float*)d_in[24];
  const float* bp2  = (const float*)d_in[25];
  __half* PW = (__half*)d_ws;          // 1.33 MB used; re-packed every call
  float* out = (float*)d_out;

  hipLaunchKernelGGL(pack_weights, dim3((PACK_TOTAL + 255) / 256), dim3(256), 0, stream,
                     Wr0, Wz0, Wh0, Wr1, Wz1, Wh1, PW);
  hipLaunchKernelGGL(grud_fused, dim3(BB), dim3(1024), 0, stream,
                     x, mask, delta, xl, sidx, emb, gx0, gh0,
                     br0, bz0, bh0, br1, bz1, bh1, Wp1, bp1, Wp2, bp2, PW, out);
}